// Round 9
// baseline (703.081 us; speedup 1.0000x reference)
//
#include <hip/hip_runtime.h>
#include <hip/hip_fp16.h>

// EllipticGNN: 2-layer GCN + linear head, f32 compute.
// fp16 pre-scaled gather rows (no wv stream, 256B rows); two-phase
// bucketed CSR fill (kills the 16x write amplification of random scatter).

constexpr int NN   = 100000;
constexpr int NE   = 1600000;
constexpr int FIN  = 165;
constexpr int HID  = 128;
constexpr int BUKSH = 7;                          // 128 nodes per bucket
constexpr int NBUK  = (NN + 127) >> BUKSH;        // 782

__global__ __launch_bounds__(256) void k_zero(int* __restrict__ c,
                                              int* __restrict__ bcur) {
    int i = blockIdx.x * 256 + threadIdx.x;
    if (i < NN) c[i] = 0;
    if (i < NBUK) bcur[i] = 0;
}

__global__ __launch_bounds__(256) void k_hist(const int* __restrict__ dst,
                                              int* __restrict__ c) {
    int i = blockIdx.x * 256 + threadIdx.x;
    if (i < NE) atomicAdd(&c[dst[i]], 1);
}

__global__ __launch_bounds__(256) void k_dinv(const int* __restrict__ c,
                                              float* __restrict__ dinv) {
    int i = blockIdx.x * 256 + threadIdx.x;
    if (i < NN) dinv[i] = rsqrtf((float)c[i] + 1.0f);   // +1 self-loop
}

__global__ __launch_bounds__(256) void k_scanA(const int* __restrict__ c,
                                               int* __restrict__ rowptr,
                                               int* __restrict__ bsum) {
    __shared__ int s[256];
    int t = threadIdx.x;
    int i = blockIdx.x * 256 + t;
    int v = (i < NN) ? c[i] : 0;
    s[t] = v; __syncthreads();
    for (int off = 1; off < 256; off <<= 1) {
        int add = (t >= off) ? s[t - off] : 0;
        __syncthreads();
        s[t] += add;
        __syncthreads();
    }
    if (i < NN) rowptr[i] = s[t] - v;
    if (t == 255) bsum[blockIdx.x] = s[255];
}

__global__ __launch_bounds__(512) void k_scanB(int* __restrict__ bsum, int nb) {
    __shared__ int s[512];
    int t = threadIdx.x;
    int v = (t < nb) ? bsum[t] : 0;
    s[t] = v; __syncthreads();
    for (int off = 1; off < 512; off <<= 1) {
        int add = (t >= off) ? s[t - off] : 0;
        __syncthreads();
        s[t] += add;
        __syncthreads();
    }
    if (t < nb) bsum[t] = s[t] - v;
}

__global__ __launch_bounds__(256) void k_scanC(int* __restrict__ rowptr,
                                               const int* __restrict__ bsum) {
    int i = blockIdx.x * 256 + threadIdx.x;
    if (i < NN) rowptr[i] += bsum[blockIdx.x];
    if (i == 0) rowptr[NN] = NE;
}

// Phase 1: scatter edge -> dst bucket region (appends are sequential per
// bucket => full-line writes). packed = src | (dst&127)<<17  (26 bits).
__global__ __launch_bounds__(256) void k_bucket(const int* __restrict__ src,
                                                const int* __restrict__ dst,
                                                const int* __restrict__ rowptr,
                                                int* __restrict__ bcur,
                                                unsigned* __restrict__ tmp) {
    int e = blockIdx.x * 256 + threadIdx.x;
    if (e >= NE) return;
    int s = src[e], d = dst[e];
    int b = d >> BUKSH;
    int pos = rowptr[b << BUKSH] + atomicAdd(&bcur[b], 1);
    tmp[pos] = (unsigned)s | ((unsigned)(d & 127) << 17);
}

// Phase 2: one block per bucket; LDS cursors; col writes land in the
// bucket's compact (~4KB) window.
__global__ __launch_bounds__(256) void k_fillb(const unsigned* __restrict__ tmp,
                                               const int* __restrict__ rowptr,
                                               int* __restrict__ col) {
    __shared__ int lcur[128];
    const int b = blockIdx.x;
    const int node0 = b << BUKSH;
    const int t = threadIdx.x;
    if (t < 128) lcur[t] = 0;
    __syncthreads();
    const int beg = rowptr[node0];
    const int endn = (node0 + 128 < NN) ? node0 + 128 : NN;
    const int end = rowptr[endn];
    for (int k = beg + t; k < end; k += 256) {
        unsigned pk = tmp[k];
        int s  = (int)(pk & 0x1FFFFu);
        int dl = (int)(pk >> 17);
        int pos = rowptr[node0 + dl] + atomicAdd(&lcur[dl], 1);
        col[pos] = s;
    }
}

// Tiled GEMM: Yh[row][c] = fp16( dinv[row] * (X[row] @ W)[c] ).
template<int K, int KP, bool VEC4>
__global__ __launch_bounds__(256) void k_gemm_h(const float* __restrict__ X,
                                                const float* __restrict__ W,
                                                const float* __restrict__ dinv,
                                                __half* __restrict__ Yh) {
    __shared__ float Xs[64 * KP];
    const int tid = threadIdx.x;
    const long base = (long)blockIdx.x * 64;
    const int rows = (NN - base < 64) ? (int)(NN - base) : 64;

    if (VEC4) {
        const float4* Xg = (const float4*)(X + base * K);
        const int tot4 = rows * (K / 4);
        for (int i = tid; i < tot4; i += 256) {
            int r = i / (K / 4), c4 = i % (K / 4);
            *(float4*)&Xs[r * KP + c4 * 4] = Xg[i];
        }
    } else {
        const int tot = rows * K;
        const float* Xg = X + base * K;
        for (int i = tid; i < tot; i += 256) {
            int r = i / K, c = i % K;
            Xs[r * KP + c] = Xg[i];
        }
    }
    __syncthreads();

    const int cg = tid & 31;
    const int rg = tid >> 5;
    const float* Wp = W + 4 * cg;
    const float* Xrow = &Xs[rg * 8 * KP];

    float acc[8][4];
#pragma unroll
    for (int r = 0; r < 8; ++r)
#pragma unroll
        for (int c = 0; c < 4; ++c) acc[r][c] = 0.0f;

    int k = 0;
    for (; k + 4 <= K; k += 4) {
        float4 w0 = *(const float4*)(Wp + (k + 0) * HID);
        float4 w1 = *(const float4*)(Wp + (k + 1) * HID);
        float4 w2 = *(const float4*)(Wp + (k + 2) * HID);
        float4 w3 = *(const float4*)(Wp + (k + 3) * HID);
#pragma unroll
        for (int r = 0; r < 8; ++r) {
            float4 xv = *(const float4*)&Xrow[r * KP + k];
            acc[r][0] += xv.x * w0.x + xv.y * w1.x + xv.z * w2.x + xv.w * w3.x;
            acc[r][1] += xv.x * w0.y + xv.y * w1.y + xv.z * w2.y + xv.w * w3.y;
            acc[r][2] += xv.x * w0.z + xv.y * w1.z + xv.z * w2.z + xv.w * w3.z;
            acc[r][3] += xv.x * w0.w + xv.y * w1.w + xv.z * w2.w + xv.w * w3.w;
        }
    }
    for (; k < K; ++k) {
        float4 wt = *(const float4*)(Wp + k * HID);
#pragma unroll
        for (int r = 0; r < 8; ++r) {
            float xs = Xrow[r * KP + k];
            acc[r][0] += xs * wt.x;
            acc[r][1] += xs * wt.y;
            acc[r][2] += xs * wt.z;
            acc[r][3] += xs * wt.w;
        }
    }

#pragma unroll
    for (int r = 0; r < 8; ++r) {
        long row = base + rg * 8 + r;
        if (row < NN) {
            float d = dinv[row];
            __half2 p0 = __floats2half2_rn(acc[r][0] * d, acc[r][1] * d);
            __half2 p1 = __floats2half2_rn(acc[r][2] * d, acc[r][3] * d);
            uint2 uv;
            uv.x = *reinterpret_cast<unsigned int*>(&p0);
            uv.y = *reinterpret_cast<unsigned int*>(&p1);
            *reinterpret_cast<uint2*>(&Yh[row * HID + 4 * cg]) = uv;
        }
    }
}

// Gather sum of pre-scaled fp16 rows (incl. self) for node i; lane j owns
// cols {2j,2j+1}.
__device__ __forceinline__ void gather_row_h(const __half2* __restrict__ H2,
                                             const int* __restrict__ rowptr,
                                             const int* __restrict__ col,
                                             int i, int j,
                                             float& a0, float& a1) {
    int k = rowptr[i];
    const int end = rowptr[i + 1];
    float2 self = __half22float2(H2[(size_t)i * 64 + j]);
    a0 = self.x;
    a1 = self.y;
    for (; k + 8 <= end; k += 8) {
        int s[8];
#pragma unroll
        for (int u = 0; u < 8; ++u)
            s[u] = __builtin_nontemporal_load(&col[k + u]);
        __half2 h[8];
#pragma unroll
        for (int u = 0; u < 8; ++u) h[u] = H2[(size_t)s[u] * 64 + j];
#pragma unroll
        for (int u = 0; u < 8; ++u) {
            float2 f = __half22float2(h[u]);
            a0 += f.x;
            a1 += f.y;
        }
    }
    for (; k < end; ++k) {
        int cs = __builtin_nontemporal_load(&col[k]);
        float2 f = __half22float2(H2[(size_t)cs * 64 + j]);
        a0 += f.x;
        a1 += f.y;
    }
}

// aggA: wave per 8 nodes; gather + b1 + relu -> LDS; mini-GEMM x W2;
// epilogue pre-scales by di, stores fp16 qhat.
__global__ __launch_bounds__(64) void k_aggA(const __half* __restrict__ Hh,
                                             const int* __restrict__ rowptr,
                                             const int* __restrict__ col,
                                             const float* __restrict__ dinv,
                                             const float* __restrict__ b1,
                                             const float* __restrict__ W2,
                                             __half* __restrict__ Qh) {
    __shared__ float vlds[8 * 128];
    const int j = threadIdx.x;                    // 0..63
    const int base = blockIdx.x * 8;
    const __half2* H2 = (const __half2*)Hh;
    const float2 bb = ((const float2*)b1)[j];

    float dloc[8];
#pragma unroll
    for (int n = 0; n < 8; ++n) dloc[n] = dinv[base + n];

#pragma unroll
    for (int n = 0; n < 8; ++n) {
        const int i = base + n;
        const float di = dloc[n];
        float a0, a1;
        gather_row_h(H2, rowptr, col, i, j, a0, a1);
        float r0 = fmaxf(di * a0 + bb.x, 0.0f);
        float r1 = fmaxf(di * a1 + bb.y, 0.0f);
        *(float2*)&vlds[n * 128 + 2 * j] = make_float2(r0, r1);
    }
    __syncthreads();

    float2 acc[8];
#pragma unroll
    for (int n = 0; n < 8; ++n) acc[n] = make_float2(0.f, 0.f);
    const float* Wp = W2 + 2 * j;
    for (int k4 = 0; k4 < 32; ++k4) {
        float2 w0 = *(const float2*)(Wp + (k4 * 4 + 0) * HID);
        float2 w1 = *(const float2*)(Wp + (k4 * 4 + 1) * HID);
        float2 w2 = *(const float2*)(Wp + (k4 * 4 + 2) * HID);
        float2 w3 = *(const float2*)(Wp + (k4 * 4 + 3) * HID);
#pragma unroll
        for (int n = 0; n < 8; ++n) {
            float4 v = *(const float4*)&vlds[n * 128 + k4 * 4];  // broadcast
            acc[n].x += v.x * w0.x + v.y * w1.x + v.z * w2.x + v.w * w3.x;
            acc[n].y += v.x * w0.y + v.y * w1.y + v.z * w2.y + v.w * w3.y;
        }
    }
#pragma unroll
    for (int n = 0; n < 8; ++n) {
        __half2 p = __floats2half2_rn(acc[n].x * dloc[n], acc[n].y * dloc[n]);
        ((__half2*)Qh)[(size_t)(base + n) * 64 + j] = p;
    }
}

// aggB: wave per 4 nodes; gather qhat, relu, fused head.
__global__ __launch_bounds__(64) void k_aggB(const __half* __restrict__ Qh,
                                             const int* __restrict__ rowptr,
                                             const int* __restrict__ col,
                                             const float* __restrict__ dinv,
                                             const float* __restrict__ b2,
                                             const float* __restrict__ W3,
                                             const float* __restrict__ b3,
                                             float* __restrict__ out) {
    const int j = threadIdx.x;
    const int base = blockIdx.x * 4;
    const __half2* Q2 = (const __half2*)Qh;
    const float2 bb = ((const float2*)b2)[j];
    const float4 w3v = *(const float4*)&W3[2 * j * 2];
    const float b30 = b3[0], b31 = b3[1];

#pragma unroll
    for (int n = 0; n < 4; ++n) {
        const int i = base + n;
        const float di = dinv[i];
        float a0, a1;
        gather_row_h(Q2, rowptr, col, i, j, a0, a1);
        float r0 = fmaxf(di * a0 + bb.x, 0.0f);
        float r1 = fmaxf(di * a1 + bb.y, 0.0f);
        float p0 = r0 * w3v.x + r1 * w3v.z;
        float p1 = r0 * w3v.y + r1 * w3v.w;
#pragma unroll
        for (int m = 1; m < 64; m <<= 1) {
            p0 += __shfl_xor(p0, m);
            p1 += __shfl_xor(p1, m);
        }
        if (j == 0)
            ((float2*)out)[i] = make_float2(p0 + b30, p1 + b31);
    }
}

extern "C" void kernel_launch(void* const* d_in, const int* in_sizes, int n_in,
                              void* d_out, int out_size, void* d_ws, size_t ws_size,
                              hipStream_t stream) {
    const float* x   = (const float*)d_in[0];
    const int*   ei  = (const int*)d_in[1];
    const float* W1  = (const float*)d_in[2];
    const float* b1  = (const float*)d_in[3];
    const float* W2  = (const float*)d_in[4];
    const float* b2  = (const float*)d_in[5];
    const float* W3  = (const float*)d_in[6];
    const float* b3  = (const float*)d_in[7];
    float* out = (float*)d_out;

    const int* srcA = ei;
    const int* dstA = ei + NE;

    char* p = (char*)d_ws;
    auto alloc = [&](size_t bytes) {
        char* r = p;
        p += (bytes + 255) & ~(size_t)255;
        return r;
    };
    float*    dinv   = (float*)alloc(NN * 4);
    int*      counts = (int*)  alloc(NN * 4);
    int*      rowptr = (int*)  alloc((NN + 1) * 4);
    int*      bsum   = (int*)  alloc(512 * 4);
    int*      bcur   = (int*)  alloc(NBUK * 4);
    unsigned* tmp    = (unsigned*)alloc((size_t)NE * 4);
    int*      col    = (int*)  alloc((size_t)NE * 4);
    __half*   hhat   = (__half*)alloc((size_t)NN * HID * 2);
    __half*   qhat   = (__half*)alloc((size_t)NN * HID * 2);

    const int nb_n = (NN + 255) / 256;
    const int nb_e = (NE + 255) / 256;
    const int nb_g = (NN + 63) / 64;

    // ---- CSR build ----
    k_zero<<<nb_n, 256, 0, stream>>>(counts, bcur);
    k_hist<<<nb_e, 256, 0, stream>>>(dstA, counts);
    k_dinv<<<nb_n, 256, 0, stream>>>(counts, dinv);
    k_scanA<<<nb_n, 256, 0, stream>>>(counts, rowptr, bsum);
    k_scanB<<<1, 512, 0, stream>>>(bsum, nb_n);
    k_scanC<<<nb_n, 256, 0, stream>>>(rowptr, bsum);
    k_bucket<<<nb_e, 256, 0, stream>>>(srcA, dstA, rowptr, bcur, tmp);
    k_fillb<<<NBUK, 256, 0, stream>>>(tmp, rowptr, col);

    // ---- layer 1 GEMM -> hhat (fp16, pre-scaled) ----
    k_gemm_h<FIN, 168, false><<<nb_g, 256, 0, stream>>>(x, W1, dinv, hhat);

    // ---- agg1 + b1 + relu + GEMV W2 -> qhat ----
    k_aggA<<<NN / 8, 64, 0, stream>>>(hhat, rowptr, col, dinv, b1, W2, qhat);

    // ---- agg2 + b2 + relu + head -> out ----
    k_aggB<<<NN / 4, 64, 0, stream>>>(qhat, rowptr, col, dinv, b2, W3, b3, out);
}

// Round 10
// 388.633 us; speedup vs baseline: 1.8091x; 1.8091x over previous
//
#include <hip/hip_runtime.h>
#include <hip/hip_fp16.h>

// EllipticGNN: 2-layer GCN + linear head, f32 compute.
// fp16 pre-scaled gather rows; XCD-partitioned CSR fill (each XCD owns a
// dst range -> col/cur lines are written by one XCD only, no false sharing).

constexpr int NN   = 100000;
constexpr int NE   = 1600000;
constexpr int FIN  = 165;
constexpr int HID  = 128;
constexpr int NPX  = NN / 8;            // 12500 nodes per XCD partition
constexpr int NCHUNK = 250;             // edge chunks per XCD
constexpr int EPC  = (NE + NCHUNK - 1) / NCHUNK;   // 6400 edges per chunk

__global__ __launch_bounds__(256) void k_zero_counts(int* __restrict__ c) {
    int i = blockIdx.x * 256 + threadIdx.x;
    if (i < NN) c[i] = 0;
}

__global__ __launch_bounds__(256) void k_hist(const int* __restrict__ dst,
                                              int* __restrict__ c) {
    int i = blockIdx.x * 256 + threadIdx.x;
    if (i < NE) atomicAdd(&c[dst[i]], 1);
}

__global__ __launch_bounds__(256) void k_dinv(const int* __restrict__ c,
                                              float* __restrict__ dinv) {
    int i = blockIdx.x * 256 + threadIdx.x;
    if (i < NN) dinv[i] = rsqrtf((float)c[i] + 1.0f);   // +1 self-loop
}

__global__ __launch_bounds__(256) void k_scanA(const int* __restrict__ c,
                                               int* __restrict__ rowptr,
                                               int* __restrict__ bsum) {
    __shared__ int s[256];
    int t = threadIdx.x;
    int i = blockIdx.x * 256 + t;
    int v = (i < NN) ? c[i] : 0;
    s[t] = v; __syncthreads();
    for (int off = 1; off < 256; off <<= 1) {
        int add = (t >= off) ? s[t - off] : 0;
        __syncthreads();
        s[t] += add;
        __syncthreads();
    }
    if (i < NN) rowptr[i] = s[t] - v;
    if (t == 255) bsum[blockIdx.x] = s[255];
}

__global__ __launch_bounds__(512) void k_scanB(int* __restrict__ bsum, int nb) {
    __shared__ int s[512];
    int t = threadIdx.x;
    int v = (t < nb) ? bsum[t] : 0;
    s[t] = v; __syncthreads();
    for (int off = 1; off < 512; off <<= 1) {
        int add = (t >= off) ? s[t - off] : 0;
        __syncthreads();
        s[t] += add;
        __syncthreads();
    }
    if (t < nb) bsum[t] = s[t] - v;
}

__global__ __launch_bounds__(256) void k_scanC(int* __restrict__ rowptr,
                                               const int* __restrict__ bsum,
                                               int* __restrict__ c) {
    int i = blockIdx.x * 256 + threadIdx.x;
    if (i < NN) { rowptr[i] += bsum[blockIdx.x]; c[i] = 0; }
    if (i == 0) rowptr[NN] = NE;
}

// XCD-partitioned fill: block b (XCD b&7) handles dst range
// [lo,hi) = [12500*(b&7), +12500) over edge chunk (b>>3).
__global__ __launch_bounds__(256) void k_fill_x(const int* __restrict__ src,
                                                const int* __restrict__ dst,
                                                const int* __restrict__ rowptr,
                                                int* __restrict__ cur,
                                                int* __restrict__ col) {
    const int b  = blockIdx.x;
    const int lo = (b & 7) * NPX;
    const int hi = lo + NPX;
    const int q  = b >> 3;
    const int e0 = q * EPC;
    const int e1 = (e0 + EPC < NE) ? e0 + EPC : NE;
    for (int e = e0 + threadIdx.x; e < e1; e += 256) {
        int d = dst[e];
        if (d >= lo && d < hi) {
            int s = src[e];
            int pos = rowptr[d] + atomicAdd(&cur[d], 1);
            col[pos] = s;
        }
    }
}

// Tiled GEMM: Yh[row][c] = fp16( dinv[row] * (X[row] @ W)[c] ).
template<int K, int KP, bool VEC4>
__global__ __launch_bounds__(256) void k_gemm_h(const float* __restrict__ X,
                                                const float* __restrict__ W,
                                                const float* __restrict__ dinv,
                                                __half* __restrict__ Yh) {
    __shared__ float Xs[64 * KP];
    const int tid = threadIdx.x;
    const long base = (long)blockIdx.x * 64;
    const int rows = (NN - base < 64) ? (int)(NN - base) : 64;

    if (VEC4) {
        const float4* Xg = (const float4*)(X + base * K);
        const int tot4 = rows * (K / 4);
        for (int i = tid; i < tot4; i += 256) {
            int r = i / (K / 4), c4 = i % (K / 4);
            *(float4*)&Xs[r * KP + c4 * 4] = Xg[i];
        }
    } else {
        const int tot = rows * K;
        const float* Xg = X + base * K;
        for (int i = tid; i < tot; i += 256) {
            int r = i / K, c = i % K;
            Xs[r * KP + c] = Xg[i];
        }
    }
    __syncthreads();

    const int cg = tid & 31;
    const int rg = tid >> 5;
    const float* Wp = W + 4 * cg;
    const float* Xrow = &Xs[rg * 8 * KP];

    float acc[8][4];
#pragma unroll
    for (int r = 0; r < 8; ++r)
#pragma unroll
        for (int c = 0; c < 4; ++c) acc[r][c] = 0.0f;

    int k = 0;
    for (; k + 4 <= K; k += 4) {
        float4 w0 = *(const float4*)(Wp + (k + 0) * HID);
        float4 w1 = *(const float4*)(Wp + (k + 1) * HID);
        float4 w2 = *(const float4*)(Wp + (k + 2) * HID);
        float4 w3 = *(const float4*)(Wp + (k + 3) * HID);
#pragma unroll
        for (int r = 0; r < 8; ++r) {
            float4 xv = *(const float4*)&Xrow[r * KP + k];
            acc[r][0] += xv.x * w0.x + xv.y * w1.x + xv.z * w2.x + xv.w * w3.x;
            acc[r][1] += xv.x * w0.y + xv.y * w1.y + xv.z * w2.y + xv.w * w3.y;
            acc[r][2] += xv.x * w0.z + xv.y * w1.z + xv.z * w2.z + xv.w * w3.z;
            acc[r][3] += xv.x * w0.w + xv.y * w1.w + xv.z * w2.w + xv.w * w3.w;
        }
    }
    for (; k < K; ++k) {
        float4 wt = *(const float4*)(Wp + k * HID);
#pragma unroll
        for (int r = 0; r < 8; ++r) {
            float xs = Xrow[r * KP + k];
            acc[r][0] += xs * wt.x;
            acc[r][1] += xs * wt.y;
            acc[r][2] += xs * wt.z;
            acc[r][3] += xs * wt.w;
        }
    }

#pragma unroll
    for (int r = 0; r < 8; ++r) {
        long row = base + rg * 8 + r;
        if (row < NN) {
            float d = dinv[row];
            __half2 p0 = __floats2half2_rn(acc[r][0] * d, acc[r][1] * d);
            __half2 p1 = __floats2half2_rn(acc[r][2] * d, acc[r][3] * d);
            uint2 uv;
            uv.x = *reinterpret_cast<unsigned int*>(&p0);
            uv.y = *reinterpret_cast<unsigned int*>(&p1);
            *reinterpret_cast<uint2*>(&Yh[row * HID + 4 * cg]) = uv;
        }
    }
}

// Gather sum of pre-scaled fp16 rows (incl. self) for node i; lane j owns
// cols {2j,2j+1}.
__device__ __forceinline__ void gather_row_h(const __half2* __restrict__ H2,
                                             const int* __restrict__ rowptr,
                                             const int* __restrict__ col,
                                             int i, int j,
                                             float& a0, float& a1) {
    int k = rowptr[i];
    const int end = rowptr[i + 1];
    float2 self = __half22float2(H2[(size_t)i * 64 + j]);
    a0 = self.x;
    a1 = self.y;
    for (; k + 8 <= end; k += 8) {
        int s[8];
#pragma unroll
        for (int u = 0; u < 8; ++u)
            s[u] = __builtin_nontemporal_load(&col[k + u]);
        __half2 h[8];
#pragma unroll
        for (int u = 0; u < 8; ++u) h[u] = H2[(size_t)s[u] * 64 + j];
#pragma unroll
        for (int u = 0; u < 8; ++u) {
            float2 f = __half22float2(h[u]);
            a0 += f.x;
            a1 += f.y;
        }
    }
    for (; k < end; ++k) {
        int cs = __builtin_nontemporal_load(&col[k]);
        float2 f = __half22float2(H2[(size_t)cs * 64 + j]);
        a0 += f.x;
        a1 += f.y;
    }
}

// aggA: wave per 8 nodes; gather + b1 + relu -> LDS; mini-GEMM x W2;
// epilogue pre-scales by di, stores fp16 qhat.
__global__ __launch_bounds__(64) void k_aggA(const __half* __restrict__ Hh,
                                             const int* __restrict__ rowptr,
                                             const int* __restrict__ col,
                                             const float* __restrict__ dinv,
                                             const float* __restrict__ b1,
                                             const float* __restrict__ W2,
                                             __half* __restrict__ Qh) {
    __shared__ float vlds[8 * 128];
    const int j = threadIdx.x;                    // 0..63
    const int base = blockIdx.x * 8;
    const __half2* H2 = (const __half2*)Hh;
    const float2 bb = ((const float2*)b1)[j];

    float dloc[8];
#pragma unroll
    for (int n = 0; n < 8; ++n) dloc[n] = dinv[base + n];

#pragma unroll
    for (int n = 0; n < 8; ++n) {
        const int i = base + n;
        const float di = dloc[n];
        float a0, a1;
        gather_row_h(H2, rowptr, col, i, j, a0, a1);
        float r0 = fmaxf(di * a0 + bb.x, 0.0f);
        float r1 = fmaxf(di * a1 + bb.y, 0.0f);
        *(float2*)&vlds[n * 128 + 2 * j] = make_float2(r0, r1);
    }
    __syncthreads();

    float2 acc[8];
#pragma unroll
    for (int n = 0; n < 8; ++n) acc[n] = make_float2(0.f, 0.f);
    const float* Wp = W2 + 2 * j;
    for (int k4 = 0; k4 < 32; ++k4) {
        float2 w0 = *(const float2*)(Wp + (k4 * 4 + 0) * HID);
        float2 w1 = *(const float2*)(Wp + (k4 * 4 + 1) * HID);
        float2 w2 = *(const float2*)(Wp + (k4 * 4 + 2) * HID);
        float2 w3 = *(const float2*)(Wp + (k4 * 4 + 3) * HID);
#pragma unroll
        for (int n = 0; n < 8; ++n) {
            float4 v = *(const float4*)&vlds[n * 128 + k4 * 4];  // broadcast
            acc[n].x += v.x * w0.x + v.y * w1.x + v.z * w2.x + v.w * w3.x;
            acc[n].y += v.x * w0.y + v.y * w1.y + v.z * w2.y + v.w * w3.y;
        }
    }
#pragma unroll
    for (int n = 0; n < 8; ++n) {
        __half2 p = __floats2half2_rn(acc[n].x * dloc[n], acc[n].y * dloc[n]);
        ((__half2*)Qh)[(size_t)(base + n) * 64 + j] = p;
    }
}

// aggB: wave per 4 nodes; gather qhat, relu, fused head.
__global__ __launch_bounds__(64) void k_aggB(const __half* __restrict__ Qh,
                                             const int* __restrict__ rowptr,
                                             const int* __restrict__ col,
                                             const float* __restrict__ dinv,
                                             const float* __restrict__ b2,
                                             const float* __restrict__ W3,
                                             const float* __restrict__ b3,
                                             float* __restrict__ out) {
    const int j = threadIdx.x;
    const int base = blockIdx.x * 4;
    const __half2* Q2 = (const __half2*)Qh;
    const float2 bb = ((const float2*)b2)[j];
    const float4 w3v = *(const float4*)&W3[2 * j * 2];
    const float b30 = b3[0], b31 = b3[1];

#pragma unroll
    for (int n = 0; n < 4; ++n) {
        const int i = base + n;
        const float di = dinv[i];
        float a0, a1;
        gather_row_h(Q2, rowptr, col, i, j, a0, a1);
        float r0 = fmaxf(di * a0 + bb.x, 0.0f);
        float r1 = fmaxf(di * a1 + bb.y, 0.0f);
        float p0 = r0 * w3v.x + r1 * w3v.z;
        float p1 = r0 * w3v.y + r1 * w3v.w;
#pragma unroll
        for (int m = 1; m < 64; m <<= 1) {
            p0 += __shfl_xor(p0, m);
            p1 += __shfl_xor(p1, m);
        }
        if (j == 0)
            ((float2*)out)[i] = make_float2(p0 + b30, p1 + b31);
    }
}

extern "C" void kernel_launch(void* const* d_in, const int* in_sizes, int n_in,
                              void* d_out, int out_size, void* d_ws, size_t ws_size,
                              hipStream_t stream) {
    const float* x   = (const float*)d_in[0];
    const int*   ei  = (const int*)d_in[1];
    const float* W1  = (const float*)d_in[2];
    const float* b1  = (const float*)d_in[3];
    const float* W2  = (const float*)d_in[4];
    const float* b2  = (const float*)d_in[5];
    const float* W3  = (const float*)d_in[6];
    const float* b3  = (const float*)d_in[7];
    float* out = (float*)d_out;

    const int* srcA = ei;
    const int* dstA = ei + NE;

    char* p = (char*)d_ws;
    auto alloc = [&](size_t bytes) {
        char* r = p;
        p += (bytes + 255) & ~(size_t)255;
        return r;
    };
    float*  dinv   = (float*)alloc(NN * 4);
    int*    counts = (int*)  alloc(NN * 4);          // reused as fill cursor
    int*    rowptr = (int*)  alloc((NN + 1) * 4);
    int*    bsum   = (int*)  alloc(512 * 4);
    int*    col    = (int*)  alloc((size_t)NE * 4);
    __half* hhat   = (__half*)alloc((size_t)NN * HID * 2);
    __half* qhat   = (__half*)alloc((size_t)NN * HID * 2);

    const int nb_n = (NN + 255) / 256;
    const int nb_e = (NE + 255) / 256;
    const int nb_g = (NN + 63) / 64;

    // ---- CSR build ----
    k_zero_counts<<<nb_n, 256, 0, stream>>>(counts);
    k_hist<<<nb_e, 256, 0, stream>>>(dstA, counts);
    k_dinv<<<nb_n, 256, 0, stream>>>(counts, dinv);
    k_scanA<<<nb_n, 256, 0, stream>>>(counts, rowptr, bsum);
    k_scanB<<<1, 512, 0, stream>>>(bsum, nb_n);
    k_scanC<<<nb_n, 256, 0, stream>>>(rowptr, bsum, counts);
    k_fill_x<<<8 * NCHUNK, 256, 0, stream>>>(srcA, dstA, rowptr, counts, col);

    // ---- layer 1 GEMM -> hhat (fp16, pre-scaled) ----
    k_gemm_h<FIN, 168, false><<<nb_g, 256, 0, stream>>>(x, W1, dinv, hhat);

    // ---- agg1 + b1 + relu + GEMV W2 -> qhat ----
    k_aggA<<<NN / 8, 64, 0, stream>>>(hhat, rowptr, col, dinv, b1, W2, qhat);

    // ---- agg2 + b2 + relu + head -> out ----
    k_aggB<<<NN / 4, 64, 0, stream>>>(qhat, rowptr, col, dinv, b2, W3, b3, out);
}